// Round 2
// baseline (269.497 us; speedup 1.0000x reference)
//
#include <hip/hip_runtime.h>

#define NBINS 30
#define NCELL 900            // 30*30
#define HWORDS (16*NCELL)    // 14400 u32 per matrix histogram set

typedef unsigned int u32;

// monotone float<->uint encoding for atomicMin/Max on floats
__device__ __forceinline__ u32 encf(float f) {
    u32 u = __float_as_uint(f);
    return u ^ ((u32)((int)u >> 31) | 0x80000000u);
}
__device__ __forceinline__ float decf(u32 e) {
    u32 u = (e & 0x80000000u) ? (e ^ 0x80000000u) : ~e;
    return __uint_as_float(u);
}

// ws u32 layout:
//  [0] ymin_enc [1] ymax_enc
//  [2..17] umin  [18..33] smin  [34..49] umax  [50..65] smax
//  [68..69] double lpt_sum   [70..71] double mi2d_sum
//  [128 ..] global histograms: u (14400 u32), then s (14400 u32)

__global__ void k_init(u32* W) {
    size_t g = (size_t)blockIdx.x * blockDim.x + threadIdx.x;
    if (g == 0) {
        W[0] = 0xFFFFFFFFu; W[1] = 0u;
        ((double*)(W + 68))[0] = 0.0;
        ((double*)(W + 70))[0] = 0.0;
    }
    if (g < 16) { W[2 + g] = 0xFFFFFFFFu; W[18 + g] = 0xFFFFFFFFu; W[34 + g] = 0u; W[50 + g] = 0u; }
    size_t stride = (size_t)gridDim.x * blockDim.x;
    for (size_t i = g; i < 2 * HWORDS; i += stride) W[128 + i] = 0u;
}

// ---------- pass 1: per-column min/max + y min/max + L_PT ----------
__global__ __launch_bounds__(256) void k_minmax(
    const float* __restrict__ yt, const float* __restrict__ yp,
    const float* __restrict__ uv, const float* __restrict__ sv,
    int N, u32* W)
{
    const float INF = __builtin_inff();
    float umn[4], umx[4], smn[4], smx[4];
#pragma unroll
    for (int k = 0; k < 4; k++) { umn[k] = INF; umx[k] = -INF; smn[k] = INF; smx[k] = -INF; }

    size_t g = (size_t)blockIdx.x * 256 + threadIdx.x;
    size_t stride = (size_t)gridDim.x * 256;
    size_t nv4 = (size_t)N * 4;  // 16 floats/row => 4 float4 per row
    const float4* u4 = (const float4*)uv;
    const float4* s4 = (const float4*)sv;
    // stride % 4 == 0, so each thread always sees column group 4*(g&3)
    for (size_t i = g; i < nv4; i += stride) {
        float4 a = u4[i];
        umn[0] = fminf(umn[0], a.x); umx[0] = fmaxf(umx[0], a.x);
        umn[1] = fminf(umn[1], a.y); umx[1] = fmaxf(umx[1], a.y);
        umn[2] = fminf(umn[2], a.z); umx[2] = fmaxf(umx[2], a.z);
        umn[3] = fminf(umn[3], a.w); umx[3] = fmaxf(umx[3], a.w);
        float4 b = s4[i];
        smn[0] = fminf(smn[0], b.x); smx[0] = fmaxf(smx[0], b.x);
        smn[1] = fminf(smn[1], b.y); smx[1] = fmaxf(smx[1], b.y);
        smn[2] = fminf(smn[2], b.z); smx[2] = fmaxf(smx[2], b.z);
        smn[3] = fminf(smn[3], b.w); smx[3] = fmaxf(smx[3], b.w);
    }
    float ymn = INF, ymx = -INF, lpt = 0.0f;
    for (size_t i = g; i < (size_t)N; i += stride) {
        float y = yp[i];
        ymn = fminf(ymn, y); ymx = fmaxf(ymx, y);
        lpt += fabsf(yt[i] - y);
    }

    // wave reduce: column classes keyed by lane&3
#pragma unroll
    for (int m = 4; m < 64; m <<= 1) {
#pragma unroll
        for (int k = 0; k < 4; k++) {
            umn[k] = fminf(umn[k], __shfl_xor(umn[k], m));
            umx[k] = fmaxf(umx[k], __shfl_xor(umx[k], m));
            smn[k] = fminf(smn[k], __shfl_xor(smn[k], m));
            smx[k] = fmaxf(smx[k], __shfl_xor(smx[k], m));
        }
    }
#pragma unroll
    for (int m = 1; m < 64; m <<= 1) {
        ymn = fminf(ymn, __shfl_xor(ymn, m));
        ymx = fmaxf(ymx, __shfl_xor(ymx, m));
        lpt += __shfl_xor(lpt, m);
    }

    __shared__ float LUmn[64], LUmx[64], LSmn[64], LSmx[64];
    __shared__ float LY[4][3];
    int wave = threadIdx.x >> 6, lane = threadIdx.x & 63;
    if (lane < 4) {
#pragma unroll
        for (int k = 0; k < 4; k++) {
            LUmn[wave * 16 + lane * 4 + k] = umn[k];
            LUmx[wave * 16 + lane * 4 + k] = umx[k];
            LSmn[wave * 16 + lane * 4 + k] = smn[k];
            LSmx[wave * 16 + lane * 4 + k] = smx[k];
        }
    }
    if (lane == 0) { LY[wave][0] = ymn; LY[wave][1] = ymx; LY[wave][2] = lpt; }
    __syncthreads();
    if (threadIdx.x < 16) {
        int t = threadIdx.x;
        float a;
        a = fminf(fminf(LUmn[t], LUmn[16 + t]), fminf(LUmn[32 + t], LUmn[48 + t]));
        atomicMin(&W[2 + t], encf(a));
        a = fminf(fminf(LSmn[t], LSmn[16 + t]), fminf(LSmn[32 + t], LSmn[48 + t]));
        atomicMin(&W[18 + t], encf(a));
        a = fmaxf(fmaxf(LUmx[t], LUmx[16 + t]), fmaxf(LUmx[32 + t], LUmx[48 + t]));
        atomicMax(&W[34 + t], encf(a));
        a = fmaxf(fmaxf(LSmx[t], LSmx[16 + t]), fmaxf(LSmx[32 + t], LSmx[48 + t]));
        atomicMax(&W[50 + t], encf(a));
    } else if (threadIdx.x == 64) {
        float a = fminf(fminf(LY[0][0], LY[1][0]), fminf(LY[2][0], LY[3][0]));
        atomicMin(&W[0], encf(a));
        a = fmaxf(fmaxf(LY[0][1], LY[1][1]), fmaxf(LY[2][1], LY[3][1]));
        atomicMax(&W[1], encf(a));
        double l = (double)LY[0][2] + (double)LY[1][2] + (double)LY[2][2] + (double)LY[3][2];
        atomicAdd((double*)(W + 68), l);
    }
}

// ---------- pass 2: 2-D histograms, np.histogram-exact binning ----------
__global__ __launch_bounds__(512) void k_hist(
    const float* __restrict__ yp, const float* __restrict__ uv, const float* __restrict__ sv,
    int N, const u32* __restrict__ W, u32* __restrict__ gh)
{
    __shared__ u32 hist[HWORDS];
    __shared__ float ex[16][32];   // 31 edges per col (+pad)
    __shared__ float ey[32];
    __shared__ float emn[16], esc[16];
    __shared__ float yp0[2];       // ymn, ysc
    int mat = blockIdx.y;
    const float* src = mat ? sv : uv;

    for (int i = threadIdx.x; i < HWORDS; i += 512) hist[i] = 0;
    if (threadIdx.x < 16) {
        int j = threadIdx.x;
        float mn = decf(W[2 + mat * 16 + j]);
        float mx = decf(W[34 + mat * 16 + j]);
        float step = (mx - mn) / 30.0f;
        for (int m = 0; m < 31; m++) ex[j][m] = __fadd_rn(__fmul_rn((float)m, step), mn);
        ex[j][30] = mx;            // np.linspace endpoint
        emn[j] = mn;
        esc[j] = (mx > mn) ? 30.0f / (mx - mn) : 0.0f;
    } else if (threadIdx.x == 16) {
        float mn = decf(W[0]), mx = decf(W[1]);
        float step = (mx - mn) / 30.0f;
        for (int m = 0; m < 31; m++) ey[m] = __fadd_rn(__fmul_rn((float)m, step), mn);
        ey[30] = mx;
        yp0[0] = mn;
        yp0[1] = (mx > mn) ? 30.0f / (mx - mn) : 0.0f;
    }
    __syncthreads();

    float ymn = yp0[0], ysc = yp0[1];
    int rpb = (N + gridDim.x - 1) / gridDim.x;
    int r0 = blockIdx.x * rpb;
    int r1 = r0 + rpb; if (r1 > N) r1 = N;
    for (int row = r0 + threadIdx.x; row < r1; row += 512) {
        float y = yp[row];
        int yb = (int)__fmul_rn(__fsub_rn(y, ymn), ysc);
        if (yb > 29) yb = 29;
        if (y < ey[yb]) yb--;
        if (yb != 29 && y >= ey[yb + 1]) yb++;

        const float4* p = (const float4*)(src + (size_t)row * 16);
        float4 q0 = p[0], q1 = p[1], q2 = p[2], q3 = p[3];
        float v[16] = {q0.x, q0.y, q0.z, q0.w, q1.x, q1.y, q1.z, q1.w,
                       q2.x, q2.y, q2.z, q2.w, q3.x, q3.y, q3.z, q3.w};
#pragma unroll
        for (int j = 0; j < 16; j++) {
            float vv = v[j];
            int b = (int)__fmul_rn(__fsub_rn(vv, emn[j]), esc[j]);
            if (b > 29) b = 29;
            if (vv < ex[j][b]) b--;
            if (b != 29 && vv >= ex[j][b + 1]) b++;
            atomicAdd(&hist[j * NCELL + b * NBINS + yb], 1u);
        }
    }
    __syncthreads();

    u32* dst = gh + (size_t)mat * HWORDS;
    for (int i = threadIdx.x; i < HWORDS; i += 512) {
        u32 c = hist[i];
        if (c) atomicAdd(&dst[i], c);
    }
}

// ---------- per-histogram MI with reference EPS semantics (32 blocks) ----------
__global__ __launch_bounds__(256) void k_mi(
    const u32* __restrict__ gh, int N, u32* W)
{
    __shared__ float C[NCELL];
    __shared__ float rsums[NBINS], csums[NBINS];
    __shared__ double red[4];
    int h = blockIdx.x;
    int mat = h >> 4, col = h & 15;
    const u32* src = gh + (size_t)mat * HWORDS + (size_t)col * NCELL;

    for (int c = threadIdx.x; c < NCELL; c += blockDim.x) C[c] = (float)src[c];
    __syncthreads();
    if (threadIdx.x < NBINS) {
        float s = 0;
        for (int j = 0; j < NBINS; j++) s += C[threadIdx.x * NBINS + j];
        rsums[threadIdx.x] = s;
    } else if (threadIdx.x >= 32 && threadIdx.x < 32 + NBINS) {
        int j = threadIdx.x - 32;
        float s = 0;
        for (int i = 0; i < NBINS; i++) s += C[i * NBINS + j];
        csums[j] = s;
    }
    __syncthreads();

    const float n = (float)N;
    double acc = 0.0;
    for (int c = threadIdx.x; c < NCELL; c += blockDim.x) {
        int i = c / NBINS, j = c % NBINS;
        float pxy = (C[c] > 0.0f) ? (C[c] / n) : 1e-10f;
        float px  = (rsums[i] > 0.0f) ? (rsums[i] / n) : 1e-10f;
        float py  = (csums[j] > 0.0f) ? (csums[j] / n) : 1e-10f;
        acc += (double)(pxy * logf(pxy / (px * py)));
    }
#pragma unroll
    for (int o = 32; o > 0; o >>= 1) acc += __shfl_xor(acc, o);
    int wid = threadIdx.x >> 6;
    if ((threadIdx.x & 63) == 0) red[wid] = acc;
    __syncthreads();
    if (threadIdx.x == 0) {
        double t = red[0] + red[1] + red[2] + red[3];
        atomicAdd((double*)(W + 70), t);
    }
}

// ---------- mi_us on first 16 rows + final combine ----------
__global__ void k_final(const float* __restrict__ uv, const float* __restrict__ sv,
                        const u32* __restrict__ W, int N, float* out)
{
    __shared__ double mis[16];
    int t = threadIdx.x;
    if (t < 16) {
        float uval[16], sval[16];
#pragma unroll
        for (int k = 0; k < 16; k++) { uval[k] = uv[t * 16 + k]; sval[k] = sv[t * 16 + k]; }
        float umn = uval[0], umx = uval[0], smn = sval[0], smx = sval[0];
#pragma unroll
        for (int k = 1; k < 16; k++) {
            umn = fminf(umn, uval[k]); umx = fmaxf(umx, uval[k]);
            smn = fminf(smn, sval[k]); smx = fmaxf(smx, sval[k]);
        }
        // np.linspace(min,max,30) in f32: e[m]=m*step+min, e[29]=max
        float ue[30], se[30];
        float ustep = (umx - umn) / 29.0f, sstep = (smx - smn) / 29.0f;
        for (int m = 0; m < 30; m++) {
            ue[m] = __fadd_rn(__fmul_rn((float)m, ustep), umn);
            se[m] = __fadd_rn(__fmul_rn((float)m, sstep), smn);
        }
        ue[29] = umx; se[29] = smx;
        // label = searchsorted(edges, v, 'right') = # edges <= v
        int lu[16], ls[16];
#pragma unroll
        for (int k = 0; k < 16; k++) {
            int c = 0, c2 = 0;
            for (int m = 0; m < 30; m++) {
                c  += (ue[m] <= uval[k]) ? 1 : 0;
                c2 += (se[m] <= sval[k]) ? 1 : 0;
            }
            lu[k] = c; ls[k] = c2;
        }
        // sklearn MI point-wise: sum_k (1/n) log(cc*n/(cu*cs))
        double mi = 0.0;
#pragma unroll
        for (int k = 0; k < 16; k++) {
            int cu = 0, cs2 = 0, cc = 0;
#pragma unroll
            for (int j = 0; j < 16; j++) {
                int bu = (lu[j] == lu[k]) ? 1 : 0;
                int bs = (ls[j] == ls[k]) ? 1 : 0;
                cu += bu; cs2 += bs; cc += (bu & bs);
            }
            mi += log((double)(cc * 16) / ((double)cu * (double)cs2));
        }
        mis[t] = mi / 16.0;
    }
    __syncthreads();
    if (t == 0) {
        double mu = 0.0;
        for (int i = 0; i < 16; i++) mu += mis[i];
        double lpt = ((const double*)(W + 68))[0] / (double)N;
        double mi2 = ((const double*)(W + 70))[0];
        double r = lpt + 0.1 * mi2 - 0.05 * mu;
        out[0] = (float)r;
    }
}

extern "C" void kernel_launch(void* const* d_in, const int* in_sizes, int n_in,
                              void* d_out, int out_size, void* d_ws, size_t ws_size,
                              hipStream_t stream)
{
    int N = in_sizes[0];
    const float* yt = (const float*)d_in[0];
    const float* yp = (const float*)d_in[1];
    const float* uv = (const float*)d_in[4];
    const float* sv = (const float*)d_in[5];
    u32* W = (u32*)d_ws;
    u32* gh = W + 128;

    k_init<<<dim3(60), dim3(512), 0, stream>>>(W);
    k_minmax<<<dim3(512), dim3(256), 0, stream>>>(yt, yp, uv, sv, N, W);
    k_hist<<<dim3(256, 2), dim3(512), 0, stream>>>(yp, uv, sv, N, W, gh);
    k_mi<<<dim3(32), dim3(256), 0, stream>>>(gh, N, W);
    k_final<<<dim3(1), dim3(64), 0, stream>>>(uv, sv, W, N, (float*)d_out);
}